// Round 3
// baseline (620.993 us; speedup 1.0000x reference)
//
#include <hip/hip_runtime.h>
#include <hip/hip_bf16.h>
#include <math.h>
#include <stdint.h>

typedef __bf16 bf16;
typedef __bf16 bf16x8 __attribute__((ext_vector_type(8)));
typedef float  floatx4 __attribute__((ext_vector_type(4)));

#define HEADS 8
#define DH    64
#define NB    8
#define NTOK  4096
#define CDIM  512
#define MTOT  32768
#define PART_STRIDE 16777216L   // elements: 32768*512

// async global->LDS, 16B per lane; LDS dst = wave-uniform base + lane*16 (m97/m104)
__device__ __forceinline__ void gload16(const bf16* g, bf16* l) {
    __builtin_amdgcn_global_load_lds(
        (const __attribute__((address_space(1))) unsigned int*)g,
        (__attribute__((address_space(3))) unsigned int*)l,
        16, 0, 0);
}

__global__ void detect_kernel(const bf16* __restrict__ w, int* __restrict__ flag)
{
    __shared__ int cnt[256];
    int c = 0;
    for (int i = 0; i < 64; ++i) {
        float v = fabsf((float)w[threadIdx.x + i * 256]);
        if (v > 1e3f) c++;
    }
    cnt[threadIdx.x] = c;
    __syncthreads();
    if (threadIdx.x == 0) {
        int s = 0;
        for (int i = 0; i < 256; ++i) s += cnt[i];
        *flag = (s > 500) ? 1 : 0;   // 1 => inputs are fp32
    }
}

__device__ __forceinline__ void wt_body(const void* __restrict__ W, bf16* __restrict__ Wt,
                                        int K, int N, bool f32, int idx)
{
    if (idx >= K * N) return;
    int n = idx / K;
    int k = idx - n * K;
    float v = f32 ? ((const float*)W)[k * N + n] : (float)((const bf16*)W)[k * N + n];
    Wt[idx] = (bf16)v;
}

// one launch: 4 weight transposes + misc (temps + biases)
// blocks [0,3072) wq0 | [3072,6144) wq1 | [6144,7168) wp0 | [7168,8192) wp1 | 8192 misc
__global__ void prep_kernel(const void* Wq0, const void* Wq1, const void* Wp0, const void* Wp1,
                            const void* t0, const void* t1, const void* b0, const void* b1,
                            const int* __restrict__ flag, float* __restrict__ misc,
                            bf16* wtq0, bf16* wtq1, bf16* wtp0, bf16* wtp1)
{
    bool f32 = (*flag != 0);
    int blk = blockIdx.x;
    int tid = threadIdx.x;
    if (blk < 3072)      wt_body(Wq0, wtq0, 512, 1536, f32, blk * 256 + tid);
    else if (blk < 6144) wt_body(Wq1, wtq1, 512, 1536, f32, (blk - 3072) * 256 + tid);
    else if (blk < 7168) wt_body(Wp0, wtp0, 512, 512, f32, (blk - 6144) * 256 + tid);
    else if (blk < 8192) wt_body(Wp1, wtp1, 512, 512, f32, (blk - 7168) * 256 + tid);
    else {
        #define RD(p, i) (f32 ? ((const float*)(p))[i] : (float)((const bf16*)(p))[i])
        if (tid < 8) { misc[tid] = RD(t0, tid); misc[8 + tid] = RD(t1, tid); }
        for (int i = tid; i < 512; i += 256) {
            misc[16 + i]  = RD(b0, i);
            misc[528 + i] = RD(b1, i);
        }
        #undef RD
    }
}

// X (fp32 or bf16 per flag) -> Y bf16; 8 elements/thread; both streams in one launch
__global__ void cast_kernel(const void* __restrict__ X0, const void* __restrict__ X1,
                            bf16* __restrict__ Y0, bf16* __restrict__ Y1,
                            const int* __restrict__ flag)
{
    int blk = blockIdx.x;
    const void* X = (blk < 8192) ? X0 : X1;
    bf16* Y       = (blk < 8192) ? Y0 : Y1;
    size_t i = ((size_t)(blk & 8191) * 256 + threadIdx.x) * 8;
    if (*flag) {
        const float* xf = (const float*)X + i;
        float4 a = *(const float4*)xf;
        float4 b = *(const float4*)(xf + 4);
        bf16 t[8] = {(bf16)a.x, (bf16)a.y, (bf16)a.z, (bf16)a.w,
                     (bf16)b.x, (bf16)b.y, (bf16)b.z, (bf16)b.w};
        *(uint4*)(Y + i) = *(uint4*)t;
    } else {
        *(uint4*)(Y + i) = *(const uint4*)((const bf16*)X + i);
    }
}

// ---------------------------------------------------------------------------
// C = A[M][512] * Bt[N][512]^T (+bias), bf16 in, K=512 fixed.
// 256x256 tile, BK=64, 512 thr / 8 waves (2M x 4N), 8-phase pipelined schedule
// with counted vmcnt (m201 template).  NJOBS n-tiles per block (persistent):
// same A-panel re-staged from L2, one prologue+chain per job; the job-(j-1)
// epilogue (LDS-transposed, coalesced dwordx4 stores in the free lds[1][*][1]
// regions) is issued AFTER job-j's prologue loads, so VMW(18) (=2 loads + 16
// stores newer than tile-0 staging) never drains the stores. z = stream.
// ---------------------------------------------------------------------------
template<int NJOBS>
__global__ __launch_bounds__(512, 2) void gemm_bt(
    const bf16* __restrict__ A0, const bf16* __restrict__ A1,
    const bf16* __restrict__ Bt0, const bf16* __restrict__ Bt1,
    const float* __restrict__ bias0, const float* __restrict__ bias1,
    void* __restrict__ C, bf16* __restrict__ Cv0, bf16* __restrict__ Cv1,
    long cbase0, long cbase1, const int* __restrict__ cflag)
{
    __shared__ bf16 lds[2][2][2][128 * 64];   // [buf][A=0/B=1][half][row*64 + swz-slot]

    const int z = blockIdx.z;
    const bf16* A    = z ? A1 : A0;
    const bf16* Btz  = z ? Bt1 : Bt0;
    const float* bias = z ? bias1 : bias0;
    bf16* Cvz        = z ? Cv1 : Cv0;
    const long c_base = z ? cbase1 : cbase0;

    const int tid  = threadIdx.x;
    const int lane = tid & 63;
    const int w    = tid >> 6;
    const int wmi  = w >> 2;        // 0..1 : wave M-half
    const int wni  = w & 3;         // 0..3 : wave N-quarter
    const int l15  = lane & 15;
    const int quad = lane >> 4;

    const int m0 = blockIdx.x * 256;

    // staging: inst i in {0,1}: local row = w*16 + i*8 + (lane>>3), phys slot p = lane&7,
    // fetch logical 16B slot s = p ^ (row&7)  (row&7 invariant under +8)
    const int rl0 = w * 16 + (lane >> 3);
    const int swz = ((lane & 7) ^ (rl0 & 7)) * 8;      // element offset of fetched chunk
    const bf16* Abase = A + (size_t)(m0 + rl0) * 512 + swz;
    const bf16* Bbase = nullptr;                        // per job
    const int ldst0 = w * 1024;                         // LDS element offset, inst0

    // compute side: logical slot s = ks*4+quad, phys slot = s ^ (row&7), row&7 == l15&7
    const int rxor  = l15 & 7;
    const int k0off = (quad ^ rxor) * 8;
    const int k1off = ((4 + quad) ^ rxor) * 8;
    const bf16* Ah0 = &lds[0][0][wmi][l15 * 64];
    const bf16* Ah1 = &lds[1][0][wmi][l15 * 64];
    const bf16* Bh0 = &lds[0][1][wni >> 1][((wni & 1) * 64 + l15) * 64];
    const bf16* Bh1 = &lds[1][1][wni >> 1][((wni & 1) * 64 + l15) * 64];

    // epilogue scratch: 4KB/wave inside lds[1][0][1] (waves 0-3) / lds[1][1][1] (4-7)
    bf16* eb = (bf16*)lds + ((w < 4) ? (5 * 8192 + w * 2048) : (7 * 8192 + (w - 4) * 2048));

    bf16x8 aR[4][2], bR[4][2];
    floatx4 acc[8][4] = {};

#define STAGE_A(b, h, t) do { \
    const bf16* _g = Abase + (h) * 65536 + (t) * 64; \
    gload16(_g,        &lds[b][0][h][ldst0]); \
    gload16(_g + 4096, &lds[b][0][h][ldst0 + 512]); \
} while (0)
#define STAGE_B(b, h, t) do { \
    const bf16* _g = Bbase + (h) * 65536 + (t) * 64; \
    gload16(_g,        &lds[b][1][h][ldst0]); \
    gload16(_g + 4096, &lds[b][1][h][ldst0 + 512]); \
} while (0)
#define RD_A(b, qm) do { \
    _Pragma("unroll") for (int _i = 0; _i < 4; ++_i) { \
        aR[_i][0] = *(const bf16x8*)(Ah##b + ((qm) * 4 + _i) * 1024 + k0off); \
        aR[_i][1] = *(const bf16x8*)(Ah##b + ((qm) * 4 + _i) * 1024 + k1off); \
    } \
} while (0)
#define RD_B(b, qn) do { \
    _Pragma("unroll") for (int _j = 0; _j < 2; ++_j) { \
        bR[(qn) * 2 + _j][0] = *(const bf16x8*)(Bh##b + ((qn) * 2 + _j) * 1024 + k0off); \
        bR[(qn) * 2 + _j][1] = *(const bf16x8*)(Bh##b + ((qn) * 2 + _j) * 1024 + k1off); \
    } \
} while (0)
#define MM(qm, qn) do { \
    _Pragma("unroll") for (int _i = 0; _i < 4; ++_i) \
    _Pragma("unroll") for (int _j = 0; _j < 2; ++_j) { \
        acc[(qm)*4+_i][(qn)*2+_j] = __builtin_amdgcn_mfma_f32_16x16x32_bf16( \
            aR[_i][0], bR[(qn)*2+_j][0], acc[(qm)*4+_i][(qn)*2+_j], 0, 0, 0); \
        acc[(qm)*4+_i][(qn)*2+_j] = __builtin_amdgcn_mfma_f32_16x16x32_bf16( \
            aR[_i][1], bR[(qn)*2+_j][1], acc[(qm)*4+_i][(qn)*2+_j], 0, 0, 0); \
    } \
} while (0)
#define SYNC   asm volatile("s_barrier" ::: "memory")
#define VMW(n) asm volatile("s_waitcnt vmcnt(" #n ")" ::: "memory")
#define PRIO1  __builtin_amdgcn_s_setprio(1)
#define PRIO0  __builtin_amdgcn_s_setprio(0)

#define TILE(t, b, nb, W) do { \
    RD_A(b, 0); RD_B(b, 0); \
    if ((t) + 1 < 8) STAGE_B(nb, 1, (t) + 1); \
    SYNC; PRIO1; MM(0, 0); PRIO0; SYNC; \
    RD_B(b, 1); \
    if ((t) + 1 < 8) STAGE_A(nb, 1, (t) + 1); \
    SYNC; PRIO1; MM(0, 1); PRIO0; SYNC; \
    RD_A(b, 1); \
    if ((t) + 2 < 8) STAGE_B(b, 0, (t) + 2); \
    SYNC; PRIO1; MM(1, 1); PRIO0; SYNC; \
    if ((t) + 2 < 8) STAGE_A(b, 0, (t) + 2); \
    SYNC; PRIO1; MM(1, 0); PRIO0; \
    VMW(W); SYNC; \
} while (0)

// bf16 epilogue via LDS transpose: scatter acc (+bias) into the 4KB wave slice
// (XOR ((r>>2)&3)<<4 kills the quad-row 4-way conflict), read back b128,
// store coalesced dwordx4 (128B/row segments). Then zero acc.
#define EPI_BF16(DST, PN0, BV) do { \
    bf16* _dp = (DST) + (size_t)(m0 + wmi * 128) * CDIM + ((PN0) & 511) + wni * 64; \
    _Pragma("unroll") for (int _p = 0; _p < 4; ++_p) { \
        _Pragma("unroll") for (int _f2 = 0; _f2 < 2; ++_f2) \
        _Pragma("unroll") for (int _fj = 0; _fj < 4; ++_fj) \
        _Pragma("unroll") for (int _rr = 0; _rr < 4; ++_rr) { \
            int _r32 = _f2 * 16 + quad * 4 + _rr; \
            int _cs  = (_fj * 16 + l15) ^ (((_r32 >> 2) & 3) << 4); \
            eb[_r32 * 64 + _cs] = (bf16)(acc[_p * 2 + _f2][_fj][_rr] + BV[_fj]); \
        } \
        _Pragma("unroll") for (int _q = 0; _q < 4; ++_q) { \
            int _rl = _q * 8 + (lane >> 3); \
            int _c8 = ((lane & 7) * 8) ^ (((_rl >> 2) & 3) << 4); \
            uint4 _vv = *(const uint4*)&eb[_rl * 64 + _c8]; \
            *(uint4*)(_dp + (size_t)(_p * 32 + _rl) * CDIM + (lane & 7) * 8) = _vv; \
        } \
    } \
    _Pragma("unroll") for (int _i = 0; _i < 8; ++_i) \
    _Pragma("unroll") for (int _j = 0; _j < 4; ++_j) acc[_i][_j] = (floatx4){0,0,0,0}; \
} while (0)

    float bz[4] = {0.f, 0.f, 0.f, 0.f};
    int prev_n0 = 0;

    for (int j = 0; j < NJOBS; ++j) {
        const int n0 = (blockIdx.y * NJOBS + j) * 256;
        Bbase = Btz + (size_t)(n0 + rl0) * 512 + swz;

        // prologue: tile0 (4 halves) + B0/A0 of tile1
        STAGE_A(0, 0, 0); STAGE_A(0, 1, 0); STAGE_B(0, 0, 0); STAGE_B(0, 1, 0);
        STAGE_B(1, 0, 1); STAGE_A(1, 0, 1);

        if (j > 0) {
            // epilogue of previous job (bf16 always: inter-job only for QKV).
            int pp = prev_n0 >> 9;
            bf16* dst = (pp == 2) ? Cvz : ((bf16*)C + c_base + (long)pp * PART_STRIDE);
            EPI_BF16(dst, prev_n0, bz);
            VMW(18);   // 16 stores + 2 tile-1 loads newer than tile-0 staging
        } else {
            VMW(4);
        }
        SYNC;

        TILE(0, 0, 1, 4);
        TILE(1, 1, 0, 4);
        TILE(2, 0, 1, 4);
        TILE(3, 1, 0, 4);
        TILE(4, 0, 1, 4);
        TILE(5, 1, 0, 4);
        TILE(6, 0, 1, 0);   // tail: prefetches of t+2 skipped -> drain before tile 7
        TILE(7, 1, 0, 0);

        prev_n0 = n0;
    }

    // final epilogue (pipeline fully drained; LDS free)
    const bool cf32 = cflag && (*cflag != 0);
    const int  part = prev_n0 >> 9;
    if (!cf32) {
        float bv[4];
        #pragma unroll
        for (int fj = 0; fj < 4; ++fj)
            bv[fj] = bias ? bias[prev_n0 + wni * 64 + fj * 16 + l15] : 0.0f;
        bf16* dst = (part == 2) ? Cvz : ((bf16*)C + c_base + (long)part * PART_STRIDE);
        EPI_BF16(dst, prev_n0, bv);
    } else {
        // fp32 out (proj when inputs fp32): direct 4B stores, 64B segments
        const long rowB = (long)m0 + wmi * 128 + quad * 4;
        const int  colB = (prev_n0 & 511) + wni * 64 + l15;
        float bv[4];
        #pragma unroll
        for (int fj = 0; fj < 4; ++fj)
            bv[fj] = bias ? bias[prev_n0 + wni * 64 + fj * 16 + l15] : 0.0f;
        float* Cp = (float*)C + c_base + (long)part * PART_STRIDE;
        #pragma unroll
        for (int fi = 0; fi < 8; ++fi)
            #pragma unroll
            for (int rr = 0; rr < 4; ++rr) {
                float* op = Cp + (rowB + fi * 16 + rr) * CDIM + colB;
                #pragma unroll
                for (int fj = 0; fj < 4; ++fj)
                    op[fj * 16] = acc[fi][fj][rr] + bv[fj];
            }
    }

#undef TILE
#undef STAGE_A
#undef STAGE_B
#undef RD_A
#undef RD_B
#undef MM
#undef SYNC
#undef VMW
#undef PRIO1
#undef PRIO0
#undef EPI_BF16
}

// ---------------------------------------------------------------------------
// xca_gk: G[sbh][d][e] = sum_n Q[n][d] K[n][e] via MFMA (gram over token axis),
// plus NQ/NK = diagonals of Q^T Q / K^T K. See round-2 notes.
// ---------------------------------------------------------------------------
__global__ __launch_bounds__(256) void xca_gk(
    const bf16* __restrict__ Q0, const bf16* __restrict__ K0,
    const bf16* __restrict__ Q1, const bf16* __restrict__ K1,
    float* __restrict__ G, float* __restrict__ NQ, float* __restrict__ NK)
{
    __shared__ bf16 Tq[64 * 72];
    __shared__ bf16 Tk[64 * 72];

    int bid = blockIdx.x;
    int nq4 = bid & 3;
    int h   = (bid >> 2) & 7;
    int b   = (bid >> 5) & 7;
    int s   = bid >> 8;
    int sbh = s * 64 + b * 8 + h;

    const bf16* qsrc = s ? Q1 : Q0;
    const bf16* ksrc = s ? K0 : K1;

    int tid  = threadIdx.x;
    int lane = tid & 63;
    int wv   = tid >> 6;
    int wr   = wv >> 1;
    int wc   = wv & 1;
    int l15  = lane & 15;
    int quad = lane >> 4;
    bool isQ = (wv == 0 || wv == 3);

    int m_thr = tid & 7;
    int d0    = m_thr * 8;
    int u     = tid >> 3;
    int u_w   = u ^ (m_thr << 2);
    int wbase = d0 * 72 + 2 * u_w;

    int aoff[2][2], boff[2][2];
    #pragma unroll
    for (int i = 0; i < 2; ++i) {
        int ra = wr * 32 + i * 16 + l15;
        int rb = wc * 32 + i * 16 + l15;
        #pragma unroll
        for (int ss = 0; ss < 2; ++ss) {
            int ulog = ss * 16 + quad * 4;
            aoff[i][ss] = ra * 72 + 2 * (ulog ^ ((ra >> 3) << 2));
            boff[i][ss] = rb * 72 + 2 * (ulog ^ ((rb >> 3) << 2));
        }
    }

    long gbase = (long)(b * NTOK + nq4 * 1024) * CDIM + h * DH + d0;
    const bf16* qg = qsrc + gbase;
    const bf16* kg = ksrc + gbase;

    floatx4 accG[2][2] = {};
    floatx4 accN[2] = {};

    uint4 qA, qB, kA, kB;
    {
        size_t off = (size_t)(2 * u) * CDIM;
        qA = *(const uint4*)(qg + off);
        qB = *(const uint4*)(qg + off + CDIM);
        kA = *(const uint4*)(kg + off);
        kB = *(const uint4*)(kg + off + CDIM);
    }

    for (int t = 0; t < 16; ++t) {
        __syncthreads();
        {
            const unsigned short* pa = (const unsigned short*)&qA;
            const unsigned short* pb = (const unsigned short*)&qB;
            const unsigned short* pc = (const unsigned short*)&kA;
            const unsigned short* pd = (const unsigned short*)&kB;
            #pragma unroll
            for (int j = 0; j < 8; ++j) {
                *(uint32_t*)((char*)Tq + (size_t)(wbase + j * 72) * 2) =
                    (uint32_t)pa[j] | ((uint32_t)pb[j] << 16);
                *(uint32_t*)((char*)Tk + (size_t)(wbase + j * 72) * 2) =
                    (uint32_t)pc[j] | ((uint32_t)pd[j] << 16);
            }
        }
        __syncthreads();
        if (t + 1 < 16) {
            size_t off = (size_t)((t + 1) * 64 + 2 * u) * CDIM;
            qA = *(const uint4*)(qg + off);
            qB = *(const uint4*)(qg + off + CDIM);
            kA = *(const uint4*)(kg + off);
            kB = *(const uint4*)(kg + off + CDIM);
        }
        #pragma unroll
        for (int ss = 0; ss < 2; ++ss) {
            bf16x8 a0 = *(const bf16x8*)&Tq[aoff[0][ss]];
            bf16x8 a1 = *(const bf16x8*)&Tq[aoff[1][ss]];
            bf16x8 b0 = *(const bf16x8*)&Tk[boff[0][ss]];
            bf16x8 b1 = *(const bf16x8*)&Tk[boff[1][ss]];
            accG[0][0] = __builtin_amdgcn_mfma_f32_16x16x32_bf16(a0, b0, accG[0][0], 0, 0, 0);
            accG[0][1] = __builtin_amdgcn_mfma_f32_16x16x32_bf16(a0, b1, accG[0][1], 0, 0, 0);
            accG[1][0] = __builtin_amdgcn_mfma_f32_16x16x32_bf16(a1, b0, accG[1][0], 0, 0, 0);
            accG[1][1] = __builtin_amdgcn_mfma_f32_16x16x32_bf16(a1, b1, accG[1][1], 0, 0, 0);
            if (isQ) {
                accN[0] = __builtin_amdgcn_mfma_f32_16x16x32_bf16(a0, a0, accN[0], 0, 0, 0);
                accN[1] = __builtin_amdgcn_mfma_f32_16x16x32_bf16(a1, a1, accN[1], 0, 0, 0);
            } else {
                accN[0] = __builtin_amdgcn_mfma_f32_16x16x32_bf16(b0, b0, accN[0], 0, 0, 0);
                accN[1] = __builtin_amdgcn_mfma_f32_16x16x32_bf16(b1, b1, accN[1], 0, 0, 0);
            }
        }
    }

    float* Gp = G + (size_t)sbh * 4096;
    #pragma unroll
    for (int i = 0; i < 2; ++i)
        #pragma unroll
        for (int j = 0; j < 2; ++j)
            #pragma unroll
            for (int rr = 0; rr < 4; ++rr)
                atomicAdd(&Gp[(wr * 32 + i * 16 + quad * 4 + rr) * 64 + wc * 32 + j * 16 + l15],
                          accG[i][j][rr]);

    float* Np  = isQ ? NQ : NK;
    int nbase  = (isQ ? wr : wc) * 32;
    if ((l15 >> 2) == quad) {
        atomicAdd(&Np[(size_t)sbh * 64 + nbase + l15],      accN[0][l15 & 3]);
        atomicAdd(&Np[(size_t)sbh * 64 + nbase + 16 + l15], accN[1][l15 & 3]);
    }
}

__global__ void xca_soft(const float* __restrict__ G,
                         const float* __restrict__ NQ, const float* __restrict__ NK,
                         const float* __restrict__ misc, bf16* __restrict__ P)
{
    int sbh = blockIdx.x;
    int s = sbh >> 6;
    int h = sbh & 7;
    int d = threadIdx.x;

    __shared__ float rk[64];
    rk[d] = 1.0f / fmaxf(sqrtf(NK[sbh * 64 + d]), 1e-12f);
    __syncthreads();

    float rq = 1.0f / fmaxf(sqrtf(NQ[sbh * 64 + d]), 1e-12f);
    float t  = misc[s * 8 + h];
    const float* Gr = G + (sbh * 64 + d) * 64;

    float a[64];
    float mx = -1e30f;
    #pragma unroll
    for (int e = 0; e < 64; ++e) {
        a[e] = Gr[e] * rq * rk[e] * t;
        mx = fmaxf(mx, a[e]);
    }
    float sum = 0.f;
    #pragma unroll
    for (int e = 0; e < 64; ++e) { a[e] = expf(a[e] - mx); sum += a[e]; }
    float inv = 1.0f / sum;
    bf16* Pr = P + (sbh * 64 + d) * 64;
    #pragma unroll
    for (int e = 0; e < 64; ++e) Pr[e] = (bf16)(a[e] * inv);
}

__global__ __launch_bounds__(256) void xca_pv(
    const bf16* __restrict__ V0, const bf16* __restrict__ V1,
    const bf16* __restrict__ P, bf16* __restrict__ xca)
{
    __shared__ bf16 pvs[4 * 1024];   // 2KB per wave, XOR-swizzled transpose scratch

    int bid = blockIdx.x;
    int nq4 = bid & 3;
    int h   = (bid >> 2) & 7;
    int b   = (bid >> 5) & 7;
    int s   = bid >> 8;
    int sbh = s * 64 + b * 8 + h;

    const bf16* vsrc = s ? V0 : V1;

    int tid = threadIdx.x;
    int lane = tid & 63;
    int wave = tid >> 6;
    int l15 = lane & 15;
    int quad = lane >> 4;

    bf16* eb = pvs + wave * 1024;

    const bf16* Pb = P + sbh * 4096;
    bf16x8 pf[4][2];
    #pragma unroll
    for (int i = 0; i < 4; ++i)
        #pragma unroll
        for (int h2 = 0; h2 < 2; ++h2)
            pf[i][h2] = *(const bf16x8*)&Pb[(i * 16 + l15) * 64 + h2 * 32 + quad * 8];

    int n_start = nq4 * 1024 + wave * 256;
    for (int nt = 0; nt < 16; ++nt) {
        int nb = n_start + nt * 16;
        const bf16* vp = vsrc + (long)(b * NTOK + nb + l15) * CDIM + h * DH + quad * 8;
        bf16x8 v0 = *(const bf16x8*)vp;
        bf16x8 v1 = *(const bf16x8*)(vp + 32);
        floatx4 acc[4] = {};
        #pragma unroll
        for (int i = 0; i < 4; ++i) {
            acc[i] = __builtin_amdgcn_mfma_f32_16x16x32_bf16(v0, pf[i][0], acc[i], 0, 0, 0);
            acc[i] = __builtin_amdgcn_mfma_f32_16x16x32_bf16(v1, pf[i][1], acc[i], 0, 0, 0);
        }
        // transpose 16 tok x 64 ch through LDS (conflict-free), store 128B/token
        #pragma unroll
        for (int i = 0; i < 4; ++i)
            #pragma unroll
            for (int r = 0; r < 4; ++r) {
                int tk = quad * 4 + r;
                int cs = (i * 16 + l15) ^ (((tk >> 2) & 3) << 4);
                eb[tk * 64 + cs] = (bf16)acc[i][r];
            }
        bf16* ob = xca + (long)((s * NB + b) * NTOK + nb) * CDIM + h * DH;
        #pragma unroll
        for (int p = 0; p < 2; ++p) {
            int tk = p * 8 + (lane >> 3);
            int c8 = ((lane & 7) * 8) ^ (((tk >> 2) & 3) << 4);
            uint4 vv = *(const uint4*)&eb[tk * 64 + c8];
            *(uint4*)(ob + (size_t)tk * CDIM + (lane & 7) * 8) = vv;
        }
    }
}

// ws layout (bytes), total ~208.7 MB — unchanged from previous rounds.
extern "C" void kernel_launch(void* const* d_in, const int* in_sizes, int n_in,
                              void* d_out, int out_size, void* d_ws, size_t ws_size,
                              hipStream_t stream)
{
    const void* x     = d_in[0];
    const void* x_d   = d_in[1];
    const void* Wq0   = d_in[2];
    const void* Wq1   = d_in[3];
    const void* temp0 = d_in[4];
    const void* temp1 = d_in[5];
    const void* Wp0   = d_in[6];
    const void* bp0   = d_in[7];
    const void* Wp1   = d_in[8];
    const void* bp1   = d_in[9];

    char* ws = (char*)d_ws;
    bf16*  Q0   = (bf16*)(ws);
    bf16*  K0   = (bf16*)(ws + 33554432);
    bf16*  Q1   = (bf16*)(ws + 67108864);
    bf16*  K1   = (bf16*)(ws + 100663296);
    bf16*  Xb0  = (bf16*)(ws + 134217728);
    bf16*  Xb1  = (bf16*)(ws + 167772160);
    bf16*  xca  = (bf16*)(ws + 134217728);  // overlay on Xb0+Xb1 (dead after QKV gemms)
    bf16*  wtq0 = (bf16*)(ws + 201326592);
    bf16*  wtq1 = (bf16*)(ws + 202899456);
    bf16*  wtp0 = (bf16*)(ws + 204472320);
    bf16*  wtp1 = (bf16*)(ws + 204996608);
    float* G    = (float*)(ws + 205520896);
    float* NQ   = (float*)(ws + 207618048);
    float* NK   = (float*)(ws + 207650816);
    bf16*  P    = (bf16*)(ws + 207683584);
    int*   flag = (int*)(ws + 208732160);
    float* misc = (float*)(ws + 208732224);

    bf16* V0 = (bf16*)d_out;               // V scratch in d_out (always bf16)
    bf16* V1 = (bf16*)d_out + PART_STRIDE;

    hipMemsetAsync(ws + 205520896, 0, 2162688, stream);   // zero G + NQ + NK

    detect_kernel<<<1, 256, 0, stream>>>((const bf16*)Wq0, flag);
    prep_kernel<<<8193, 256, 0, stream>>>(Wq0, Wq1, Wp0, Wp1, temp0, temp1, bp0, bp1,
                                          flag, misc, wtq0, wtq1, wtp0, wtp1);
    cast_kernel<<<16384, 256, 0, stream>>>(x, x_d, Xb0, Xb1, flag);

    // QKV both streams: parts 0/1 -> Q,K in ws; part 2 -> V scratch in d_out
    gemm_bt<3><<<dim3(128, 2, 2), 512, 0, stream>>>(
        Xb0, Xb1, wtq0, wtq1, nullptr, nullptr,
        (void*)ws, V0, V1, 0L, 2L * PART_STRIDE, nullptr);

    xca_gk<<<512, 256, 0, stream>>>(Q0, K0, Q1, K1, G, NQ, NK);
    xca_soft<<<128, 64, 0, stream>>>(G, NQ, NK, misc, P);
    xca_pv<<<512, 256, 0, stream>>>(V0, V1, P, xca);

    // proj both streams: out dtype per flag; stream-1 half at element offset PART_STRIDE
    gemm_bt<1><<<dim3(128, 2, 2), 512, 0, stream>>>(
        xca, xca + PART_STRIDE, wtp0, wtp1, misc + 16, misc + 528,
        d_out, nullptr, nullptr, 0L, PART_STRIDE, flag);
}